// Round 1
// baseline (11.468 us; speedup 1.0000x reference)
//
#include <hip/hip_runtime.h>

#define BATCH 4096
#define FEAT 128
#define WAVES_PER_BLOCK 4
#define BLOCKS (BATCH / WAVES_PER_BLOCK)   // 1024

// Kernel 1: one wave (64 lanes) per sample.
// Lane i handles feature elements [2i, 2i+1] via float2 loads (coalesced).
__global__ void __launch_bounds__(256)
centerloss_partial(const float* __restrict__ x,
                   const int* __restrict__ labels,
                   const float* __restrict__ centers,
                   float* __restrict__ partial) {
    const int wave = threadIdx.x >> 6;   // 0..3
    const int lane = threadIdx.x & 63;
    const int sample = blockIdx.x * WAVES_PER_BLOCK + wave;

    const long long lbl = (long long)labels[sample];
    const float2* xr = (const float2*)(x + (size_t)sample * FEAT);
    const float2* cr = (const float2*)(centers + (size_t)lbl * FEAT);

    const float2 xv = xr[lane];
    const float2 cv = cr[lane];
    const float dx = xv.x - cv.x;
    const float dy = xv.y - cv.y;
    float acc = dx * dx + dy * dy;

    // 64-lane wave reduction
    #pragma unroll
    for (int off = 32; off > 0; off >>= 1)
        acc += __shfl_down(acc, off, 64);

    __shared__ float s[WAVES_PER_BLOCK];
    if (lane == 0) s[wave] = acc;
    __syncthreads();
    if (threadIdx.x == 0)
        partial[blockIdx.x] = s[0] + s[1] + s[2] + s[3];
}

// Kernel 2: reduce the 1024 block partials -> mean. Deterministic order.
__global__ void __launch_bounds__(256)
centerloss_final(const float* __restrict__ partial, float* __restrict__ out) {
    float acc = 0.0f;
    for (int i = threadIdx.x; i < BLOCKS; i += 256)
        acc += partial[i];

    #pragma unroll
    for (int off = 32; off > 0; off >>= 1)
        acc += __shfl_down(acc, off, 64);

    __shared__ float s[4];
    const int wave = threadIdx.x >> 6;
    const int lane = threadIdx.x & 63;
    if (lane == 0) s[wave] = acc;
    __syncthreads();
    if (threadIdx.x == 0)
        out[0] = (s[0] + s[1] + s[2] + s[3]) * (1.0f / (float)BATCH);
}

extern "C" void kernel_launch(void* const* d_in, const int* in_sizes, int n_in,
                              void* d_out, int out_size, void* d_ws, size_t ws_size,
                              hipStream_t stream) {
    const float* x       = (const float*)d_in[0];
    const int*   labels  = (const int*)d_in[1];
    const float* centers = (const float*)d_in[2];
    float* out = (float*)d_out;
    float* partial = (float*)d_ws;   // needs BLOCKS * 4 bytes = 4 KB

    centerloss_partial<<<BLOCKS, 256, 0, stream>>>(x, labels, centers, partial);
    centerloss_final<<<1, 256, 0, stream>>>(partial, out);
}